// Round 15
// baseline (2686.581 us; speedup 1.0000x reference)
//
#include <hip/hip_runtime.h>

// Sizes (fixed): V=512, F_IN=8, H=64, DH=4, T=3, E=8192, P=64, L=8, D=68

__device__ __forceinline__ float fsig_(float x) { return 1.f / (1.f + __expf(-x)); }
__device__ __forceinline__ float ftanh_(float x) {
  float e = __expf(2.f * x);
  return 1.f - 2.f / (e + 1.f);
}
__device__ __forceinline__ float sig_(float x) { return 1.f / (1.f + expf(-x)); }

// Barrier WITHOUT vmcnt drain: LDS ordering only.
__device__ __forceinline__ void barrier_lgkm() {
  asm volatile("s_waitcnt lgkmcnt(0)\n\ts_barrier" ::: "memory");
}

// Pin a float4 into VGPRs (opaque redefinition, blocks rematerialization).
// Re-applied INSIDE the loop. Works only when the allocator's occupancy
// target permits the registers — see amdgpu_waves_per_eu on scan_kernel.
#define PIN4(v) asm volatile("" : "+v"((v).x), "+v"((v).y), "+v"((v).z), "+v"((v).w))

// async global->LDS, 4 bytes/lane: LDS dst = uniform base + lane*4.
#define GLD_LDS4(gp, lp)                                                       \
  __builtin_amdgcn_global_load_lds(                                            \
      (const __attribute__((address_space(1))) void*)(gp),                     \
      (__attribute__((address_space(3))) void*)(lp), 4, 0, 0)

// NOTE: macro params must NOT collide with float4 member names (x/y/z/w).
#define LD4(p) (*(const float4*)(p))
#define DOT4(acc, va, vb)                                                      \
  do {                                                                         \
    acc += (va).x * (vb).x; acc += (va).y * (vb).y;                            \
    acc += (va).z * (vb).z; acc += (va).w * (vb).w;                            \
  } while (0)

#define ALL16(M) M(0) M(1) M(2) M(3) M(4) M(5) M(6) M(7)                       \
                 M(8) M(9) M(10) M(11) M(12) M(13) M(14) M(15)
#define ALLQ(M) M(0,0) M(1,1) M(2,2) M(3,3) M(4,0) M(5,1) M(6,2) M(7,3)        \
                M(8,0) M(9,1) M(10,2) M(11,3) M(12,0) M(13,1) M(14,2) M(15,3)

// x[i,j,h] = sum_f adj[i,j,f] * emb[h,f]
__global__ __launch_bounds__(256) void embed_kernel(
    const float* __restrict__ adj, const float* __restrict__ emb,
    float* __restrict__ x)
{
  const int64_t row = (int64_t)blockIdx.x * 4 + (threadIdx.x >> 6);
  const int h = threadIdx.x & 63;
  const float* a = adj + row * 8;
  float acc = 0.f;
#pragma unroll
  for (int f = 0; f < 8; ++f) acc += a[f] * emb[h * 8 + f];
  x[row * 64 + h] = acc;
}

// col_sum[j,h] = sum_i x[i,j,h];  col_nz[j] = sum_i sum_h (x[i,j,h]!=0)
__global__ __launch_bounds__(256) void colsum_kernel(
    const float* __restrict__ x, float* __restrict__ col_sum,
    int* __restrict__ col_nz)
{
  const int j = blockIdx.x;
  const int h = threadIdx.x & 63;
  const int w = threadIdx.x >> 6;
  float acc = 0.f;
  int nz = 0;
  for (int i = w; i < 512; i += 4) {
    float v = x[((int64_t)i * 512 + j) * 64 + h];
    acc += v;
    nz += (v != 0.f) ? 1 : 0;
  }
  __shared__ float pacc[4][64];
  __shared__ int pnz[4];
#pragma unroll
  for (int off = 32; off > 0; off >>= 1) nz += __shfl_down(nz, off, 64);
  if (h == 0) pnz[w] = nz;
  pacc[w][h] = acc;
  __syncthreads();
  if (w == 0) {
    col_sum[j * 64 + h] = pacc[0][h] + pacc[1][h] + pacc[2][h] + pacc[3][h];
    if (h == 0) col_nz[j] = pnz[0] + pnz[1] + pnz[2] + pnz[3];
  }
}

__global__ void scatter_idx_kernel(const int* __restrict__ edges,
                                   int* __restrict__ idxmap)
{
  const int e = blockIdx.x * 256 + threadIdx.x;
  if (e < 8192) idxmap[edges[e * 2] * 512 + edges[e * 2 + 1]] = e;
}

// Per-edge message m_e, then delta_gi[e,g] = sum_h (m_e[h]-x_uv[h]) * w_ih[g,h]
__global__ __launch_bounds__(64) void edge_kernel(
    const float* __restrict__ x, const int* __restrict__ edges,
    const float* __restrict__ col_sum, const int* __restrict__ col_nz,
    const float* __restrict__ w1, const float* __restrict__ w2,
    const float* __restrict__ w3, const float* __restrict__ w_ih,
    float* __restrict__ delta_gi)
{
  const int e = blockIdx.x;
  const int h = threadIdx.x;
  const int u = edges[e * 2 + 0];
  const int v = edges[e * 2 + 1];
  __shared__ __align__(16) float xuv[64], ein[64], eout[64], dm[64];
  const float xuvh = x[((int64_t)u * 512 + v) * 64 + h];
  const float xvuh = x[((int64_t)v * 512 + u) * 64 + h];
  xuv[h] = xuvh;
  const int nz_vu = __popcll(__ballot(xvuh != 0.f));
  const int nz_uv = __popcll(__ballot(xuvh != 0.f));
  float n_in = (float)(col_nz[u] - nz_vu) / 64.f;
  if (n_in == 0.f) n_in = 1.f;
  float n_out = (float)(col_nz[v] - nz_uv) / 64.f;
  if (n_out == 0.f) n_out = 1.f;
  ein[h] = (col_sum[u * 64 + h] - xvuh) / n_in;
  eout[h] = (col_sum[v * 64 + h] - xuvh) / n_out;
  __syncthreads();
  const float4* w1r = (const float4*)(w1 + h * 64);
  const float4* w2r = (const float4*)(w2 + h * 64);
  const float4* w3r = (const float4*)(w3 + h * 64);
  const float4* xuv4 = (const float4*)xuv;
  const float4* ein4 = (const float4*)ein;
  const float4* eout4 = (const float4*)eout;
  float acc = 0.f;
#pragma unroll
  for (int kk = 0; kk < 16; ++kk) {
    float4 a = xuv4[kk], b = w1r[kk];
    acc += a.x * b.x + a.y * b.y + a.z * b.z + a.w * b.w;
    a = ein4[kk]; b = w2r[kk];
    acc += a.x * b.x + a.y * b.y + a.z * b.z + a.w * b.w;
    a = eout4[kk]; b = w3r[kk];
    acc += a.x * b.x + a.y * b.y + a.z * b.z + a.w * b.w;
  }
  const float m = fmaxf(acc, 0.f);
  dm[h] = m - xuvh;
  __syncthreads();
  const float4* dm4 = (const float4*)dm;
#pragma unroll
  for (int r = 0; r < 3; ++r) {
    const int gg = h + r * 64;
    const float4* wr = (const float4*)(w_ih + gg * 128);
    float d = 0.f;
#pragma unroll
    for (int kk = 0; kk < 16; ++kk) {
      float4 a = dm4[kk], b = wr[kk];
      d += a.x * b.x + a.y * b.y + a.z * b.z + a.w * b.w;
    }
    delta_gi[e * 192 + gg] = d;
  }
}

// ---- GRU scan v11: v9 + amdgpu_waves_per_eu(2,3). ----
// The allocator's default target is MAX achievable occupancy, so it remats
// loop-invariant weight loads to shrink VGPRs (r8-r14: VGPR 56-128 in every
// design, weights reloaded from L2 each step). Capping max waves/EU at 3
// (our actual residency: 2 blocks x 6 waves / 4 SIMDs) raises the VGPR
// budget to ~170 -> weight residency becomes the cheap choice.
#define DECL_W(i)                                                              \
  float4 W##i; {                                                               \
    float4 t0 = LD4(wg + 4 * (i));                                             \
    float4 t1 = LD4(wg + 64 + 4 * (i));                                        \
    W##i.x = t0.x + t1.x; W##i.y = t0.y + t1.y;                                \
    W##i.z = t0.z + t1.z; W##i.w = t0.w + t1.w;                                \
  }                                                                            \
  PIN4(W##i);
#define RPW(i) PIN4(W##i);
#define PX(i, q) { float4 xc = xq4[(i)]; DOT4(a##q, xc, W##i); }
#define DECL_WC(i) float4 WC##i = LD4(wc + 4 * (i)); PIN4(WC##i);
#define RPC(i) PIN4(WC##i);
#define HQ(i, q) { float4 hc = hs4[(i)]; DOT4(a##q, hc, WC##i); }

__global__ __launch_bounds__(384)
__attribute__((amdgpu_waves_per_eu(2, 3)))
void scan_kernel(
    float* __restrict__ x, const float* __restrict__ delta_gi,
    const int* __restrict__ idxmap,
    const float* __restrict__ w_ih, const float* __restrict__ w_hh,
    const float* __restrict__ b_ih, const float* __restrict__ b_hh)
{
  const int tid = threadIdx.x;
  const int wave = tid >> 6;
  const int lane = tid & 63;
  const int b = blockIdx.x;
  __shared__ __align__(16) float xring[16][64];  // 4KB ring
  __shared__ float gib[2][192];
  __shared__ float rzb[2][64];
  __shared__ __align__(16) float hs[64];
  __shared__ int idxl[512];
  float* xrow = x + (int64_t)b * 32768;

  for (int i = tid; i < 512; i += 384) idxl[i] = idxmap[b * 512 + i];
  if (tid < 64) hs[tid] = 0.f;
  if (wave == 0) {  // preload x[0..7] into ring
#pragma unroll
    for (int s = 0; s < 8; ++s) GLD_LDS4(xrow + s * 64 + lane, &xring[s][0]);
  }
  __syncthreads();  // drains wave0's vmcnt -> slots 0..7 valid; idxl/hs sealed

  if (wave < 3) {
    // ---------------- producer ----------------
    const int g = wave * 64 + lane;
    const float* wg = w_ih + g * 128;
    ALL16(DECL_W)
    const float bi = b_ih[g];
    {  // prologue: gib[0] from ring slot 0
      const float4* xq4 = (const float4*)&xring[0][0];
      float a0 = bi, a1 = 0.f, a2 = 0.f, a3 = 0.f;
      ALLQ(PX)
      float acc = (a0 + a1) + (a2 + a3);
      const int i0 = idxl[0];
      const float d0 = delta_gi[(int64_t)(i0 < 0 ? 0 : i0) * 192 + g];
      acc += (i0 >= 0) ? d0 : 0.f;
      gib[0][g] = acc;
    }
    const int i1 = idxl[1];
    float dg_cur = delta_gi[(int64_t)(i1 < 0 ? 0 : i1) * 192 + g];
    dg_cur = (i1 >= 0) ? dg_cur : 0.f;
    barrier_lgkm();  // P: gib[0] published
    for (int t = 0; t < 512; ++t) {
      ALL16(RPW)  // re-pin: weights stay register-resident
      // Phase A: gi[t+1] (slot write harmless at t=511)
      const float4* xq4 = (const float4*)&xring[(t + 1) & 15][0];
      float a0 = bi + dg_cur, a1 = 0.f, a2 = 0.f, a3 = 0.f;
      ALLQ(PX)
      gib[(t + 1) & 1][g] = (a0 + a1) + (a2 + a3);
      const int t2 = (t + 2 < 512) ? t + 2 : 511;
      const int idn = idxl[t2];
      float dgt = delta_gi[(int64_t)(idn < 0 ? 0 : idn) * 192 + g];
      dgt = (idn >= 0) ? dgt : 0.f;
      if (wave == 0) {
        const int tf = (t + 8 < 512) ? t + 8 : 511;
        GLD_LDS4(xrow + tf * 64 + lane, &xring[(t + 8) & 15][0]);
        asm volatile("s_waitcnt vmcnt(6)" ::: "memory");
      }
      barrier_lgkm();  // B1
      barrier_lgkm();  // B2
      dg_cur = dgt;
    }
  } else if (wave < 5) {
    // ---------------- consumer r (wave 3) / z (wave 4) ----------------
    const int cls = wave - 3;
    const int j = lane;
    const float* wc = w_hh + (cls * 64 + j) * 64;
    ALL16(DECL_WC)
    const float bc = b_hh[cls * 64 + j];
    __builtin_amdgcn_s_setprio(1);
    barrier_lgkm();  // P
    const float4* hs4 = (const float4*)hs;
    for (int t = 0; t < 512; ++t) {
      ALL16(RPC)  // re-pin
      const float gc = gib[t & 1][cls * 64 + j];
      float a0 = bc, a1 = 0.f, a2 = 0.f, a3 = 0.f;
      ALLQ(HQ)
      rzb[cls][j] = fsig_(gc + (a0 + a1) + (a2 + a3));
      barrier_lgkm();  // B1
      barrier_lgkm();  // B2
    }
  } else {
    // ---------------- consumer n (wave 5) ----------------
    const int j = lane;
    const float* wc = w_hh + (128 + j) * 64;
    ALL16(DECL_WC)
    const float bc = b_hh[128 + j];
    float hj = 0.f;
    __builtin_amdgcn_s_setprio(1);
    barrier_lgkm();  // P
    const float4* hs4 = (const float4*)hs;
    for (int t = 0; t < 512; ++t) {
      ALL16(RPC)  // re-pin
      const float gn = gib[t & 1][128 + j];
      float a0 = bc, a1 = 0.f, a2 = 0.f, a3 = 0.f;
      ALLQ(HQ)
      const float nacc = (a0 + a1) + (a2 + a3);
      barrier_lgkm();  // B1: r,z published
      const float r = rzb[0][j];
      const float z = rzb[1][j];
      const float nn = ftanh_(gn + r * nacc);
      hj = (1.f - z) * nn + z * hj;
      hs[j] = hj;
      xrow[t * 64 + j] = hj;
      barrier_lgkm();  // B2: h published
    }
  }
}

__global__ __launch_bounds__(64) void graphemb_kernel(
    const float* __restrict__ col_sum, float* __restrict__ graph_emb)
{
  const int h = threadIdx.x;
  float s = 0.f;
#pragma unroll 8
  for (int j = 0; j < 512; ++j) s += col_sum[j * 64 + h];
  graph_emb[h] = s * (1.f / 262144.f);
  if (h < 4) graph_emb[64 + h] = 0.f;
}

// One block per (path, direction). 7-step GRU, D=68, gates 204.
__global__ __launch_bounds__(256) void path_kernel(
    const float* __restrict__ x, const int* __restrict__ paths,
    const float* __restrict__ demands, const float* __restrict__ wd,
    const float* __restrict__ graph_emb,
    const float* __restrict__ wih_f, const float* __restrict__ whh_f,
    const float* __restrict__ bih_f, const float* __restrict__ bhh_f,
    const float* __restrict__ wih_b, const float* __restrict__ whh_b,
    const float* __restrict__ bih_b, const float* __restrict__ bhh_b,
    float* __restrict__ h_out)
{
  const int p = blockIdx.x & 63;
  const int dir = blockIdx.x >> 6;
  const int g = threadIdx.x;
  const float* w_ih = dir ? wih_b : wih_f;
  const float* w_hh = dir ? whh_b : whh_f;
  const float* bih = dir ? bih_b : bih_f;
  const float* bhh = dir ? bhh_b : bhh_f;
  __shared__ float feat[7][68], hs[68], rbuf[68], zbuf[68];
  if (g < 68) {
#pragma unroll
    for (int t = 0; t < 7; ++t) {
      const int src = paths[p * 8 + t];
      const int dst = paths[p * 8 + t + 1];
      feat[t][g] = (g < 64) ? x[((int64_t)src * 512 + dst) * 64 + g]
                            : fmaxf(demands[p] * wd[g - 64], 0.f);
    }
    hs[g] = graph_emb[g];
  }
  __syncthreads();
  for (int s = 0; s < 7; ++s) {
    const int t = dir ? (6 - s) : s;
    float acc = 0.f, hacc = 0.f;
    if (g < 204) {
      acc = bih[g];
      hacc = bhh[g];
      for (int k = 0; k < 68; ++k) {
        acc += feat[t][k] * w_ih[g * 68 + k];
        hacc += hs[k] * w_hh[g * 68 + k];
      }
    }
    if (g < 68) rbuf[g] = sig_(acc + hacc);
    else if (g < 136) zbuf[g - 68] = sig_(acc + hacc);
    __syncthreads();
    if (g >= 136 && g < 204) {
      const int j = g - 136;
      const float n = tanhf(acc + rbuf[j] * hacc);
      const float z = zbuf[j];
      const float hn = (1.f - z) * n + z * hs[j];
      hs[j] = hn;
    }
    __syncthreads();
  }
  if (g < 68) h_out[(dir * 64 + p) * 68 + g] = hs[g];
}

__global__ __launch_bounds__(64) void combine_kernel(
    const float* __restrict__ h_out, const float* __restrict__ wq,
    const float* __restrict__ bq, float* __restrict__ out)
{
  const int p = threadIdx.x;
  float l = bq[0];
#pragma unroll
  for (int d = 0; d < 68; ++d)
    l += 0.5f * (h_out[p * 68 + d] + h_out[(64 + p) * 68 + d]) * wq[d];
  float mx = l;
#pragma unroll
  for (int off = 32; off > 0; off >>= 1) mx = fmaxf(mx, __shfl_xor(mx, off, 64));
  const float e = expf(l - mx);
  float s = e;
#pragma unroll
  for (int off = 32; off > 0; off >>= 1) s += __shfl_xor(s, off, 64);
  out[p] = e / s;
}

extern "C" void kernel_launch(void* const* d_in, const int* in_sizes, int n_in,
                              void* d_out, int out_size, void* d_ws, size_t ws_size,
                              hipStream_t stream)
{
  const float* adj = (const float*)d_in[0];
  const int* edges = (const int*)d_in[1];
  const int* paths = (const int*)d_in[2];
  const float* demands = (const float*)d_in[3];
  const float* emb_w = (const float*)d_in[4];
  const float* w1s = (const float*)d_in[5];
  const float* w2s = (const float*)d_in[6];
  const float* w3s = (const float*)d_in[7];
  const float* gru_w_ih = (const float*)d_in[8];
  const float* gru_w_hh = (const float*)d_in[9];
  const float* gru_b_ih = (const float*)d_in[10];
  const float* gru_b_hh = (const float*)d_in[11];
  const float* pf_w_ih = (const float*)d_in[12];
  const float* pf_w_hh = (const float*)d_in[13];
  const float* pf_b_ih = (const float*)d_in[14];
  const float* pf_b_hh = (const float*)d_in[15];
  const float* pb_w_ih = (const float*)d_in[16];
  const float* pb_w_hh = (const float*)d_in[17];
  const float* pb_b_ih = (const float*)d_in[18];
  const float* pb_b_hh = (const float*)d_in[19];
  const float* wq = (const float*)d_in[20];
  const float* bq = (const float*)d_in[21];
  const float* wd = (const float*)d_in[22];
  float* out = (float*)d_out;

  // Workspace layout (floats): ~74.6 MB total (known-safe size)
  float* xA = (float*)d_ws;                    // 512*512*64 = 16777216
  float* col_sum = xA + 16777216;              // 32768
  int* col_nz = (int*)(col_sum + 32768);       // 512
  int* idxmap = col_nz + 512;                  // 262144
  float* delta_gi = (float*)(idxmap + 262144); // 8192*192 = 1572864
  float* graph_emb = delta_gi + 1572864;       // 68 (+pad)
  float* h_out = graph_emb + 128;              // 2*64*68 = 8704

  hipMemsetAsync(idxmap, 0xFF, 262144 * sizeof(int), stream);
  scatter_idx_kernel<<<32, 256, 0, stream>>>(edges, idxmap);
  embed_kernel<<<65536, 256, 0, stream>>>(adj, emb_w, xA);

  for (int t = 0; t < 3; ++t) {
    colsum_kernel<<<512, 256, 0, stream>>>(xA, col_sum, col_nz);
    edge_kernel<<<8192, 64, 0, stream>>>(xA, edges, col_sum, col_nz,
        w1s + t * 4096, w2s + t * 4096, w3s + t * 4096, gru_w_ih, delta_gi);
    scan_kernel<<<512, 384, 0, stream>>>(xA, delta_gi, idxmap,
        gru_w_ih, gru_w_hh, gru_b_ih, gru_b_hh);
  }

  colsum_kernel<<<512, 256, 0, stream>>>(xA, col_sum, col_nz);
  graphemb_kernel<<<1, 64, 0, stream>>>(col_sum, graph_emb);
  path_kernel<<<128, 256, 0, stream>>>(xA, paths, demands, wd, graph_emb,
      pf_w_ih, pf_w_hh, pf_b_ih, pf_b_hh,
      pb_w_ih, pb_w_hh, pb_b_ih, pb_b_hh, h_out);
  combine_kernel<<<1, 64, 0, stream>>>(h_out, wq, bq, out);
}

// Round 16
// 1862.962 us; speedup vs baseline: 1.4421x; 1.4421x over previous
//
#include <hip/hip_runtime.h>

// Sizes (fixed): V=512, F_IN=8, H=64, DH=4, T=3, E=8192, P=64, L=8, D=68

__device__ __forceinline__ float fsig_(float x) { return 1.f / (1.f + __expf(-x)); }
__device__ __forceinline__ float ftanh_(float x) {
  float e = __expf(2.f * x);
  return 1.f - 2.f / (e + 1.f);
}
__device__ __forceinline__ float sig_(float x) { return 1.f / (1.f + expf(-x)); }

// Barrier WITHOUT vmcnt drain: LDS ordering only.
__device__ __forceinline__ void barrier_lgkm() {
  asm volatile("s_waitcnt lgkmcnt(0)\n\ts_barrier" ::: "memory");
}

// Pin a float4 into VGPRs (opaque redefinition at the asm site).
#define PIN4(v) asm volatile("" : "+v"((v).x), "+v"((v).y), "+v"((v).z), "+v"((v).w))

// NOTE: macro params must NOT collide with float4 member names (x/y/z/w).
#define LD4(p) (*(const float4*)(p))
#define DOT4(acc, va, vb)                                                      \
  do {                                                                         \
    acc += (va).x * (vb).x; acc += (va).y * (vb).y;                            \
    acc += (va).z * (vb).z; acc += (va).w * (vb).w;                            \
  } while (0)

#define ALL16(M) M(0) M(1) M(2) M(3) M(4) M(5) M(6) M(7)                       \
                 M(8) M(9) M(10) M(11) M(12) M(13) M(14) M(15)
#define ALLQ(M) M(0,0) M(1,1) M(2,2) M(3,3) M(4,0) M(5,1) M(6,2) M(7,3)        \
                M(8,0) M(9,1) M(10,2) M(11,3) M(12,0) M(13,1) M(14,2) M(15,3)

// x[i,j,h] = sum_f adj[i,j,f] * emb[h,f]
__global__ __launch_bounds__(256) void embed_kernel(
    const float* __restrict__ adj, const float* __restrict__ emb,
    float* __restrict__ x)
{
  const int64_t row = (int64_t)blockIdx.x * 4 + (threadIdx.x >> 6);
  const int h = threadIdx.x & 63;
  const float* a = adj + row * 8;
  float acc = 0.f;
#pragma unroll
  for (int f = 0; f < 8; ++f) acc += a[f] * emb[h * 8 + f];
  x[row * 64 + h] = acc;
}

// col_sum[j,h] = sum_i x[i,j,h];  col_nz[j] = sum_i sum_h (x[i,j,h]!=0)
__global__ __launch_bounds__(256) void colsum_kernel(
    const float* __restrict__ x, float* __restrict__ col_sum,
    int* __restrict__ col_nz)
{
  const int j = blockIdx.x;
  const int h = threadIdx.x & 63;
  const int w = threadIdx.x >> 6;
  float acc = 0.f;
  int nz = 0;
  for (int i = w; i < 512; i += 4) {
    float v = x[((int64_t)i * 512 + j) * 64 + h];
    acc += v;
    nz += (v != 0.f) ? 1 : 0;
  }
  __shared__ float pacc[4][64];
  __shared__ int pnz[4];
#pragma unroll
  for (int off = 32; off > 0; off >>= 1) nz += __shfl_down(nz, off, 64);
  if (h == 0) pnz[w] = nz;
  pacc[w][h] = acc;
  __syncthreads();
  if (w == 0) {
    col_sum[j * 64 + h] = pacc[0][h] + pacc[1][h] + pacc[2][h] + pacc[3][h];
    if (h == 0) col_nz[j] = pnz[0] + pnz[1] + pnz[2] + pnz[3];
  }
}

__global__ void scatter_idx_kernel(const int* __restrict__ edges,
                                   int* __restrict__ idxmap)
{
  const int e = blockIdx.x * 256 + threadIdx.x;
  if (e < 8192) idxmap[edges[e * 2] * 512 + edges[e * 2 + 1]] = e;
}

// Per-edge message m_e, then delta_gi[e,g] = sum_h (m_e[h]-x_uv[h]) * w_ih[g,h]
// 4 edges per block, one 64-lane wave each (ballot/popc are per-wave).
__global__ __launch_bounds__(256) void edge_kernel(
    const float* __restrict__ x, const int* __restrict__ edges,
    const float* __restrict__ col_sum, const int* __restrict__ col_nz,
    const float* __restrict__ w1, const float* __restrict__ w2,
    const float* __restrict__ w3, const float* __restrict__ w_ih,
    float* __restrict__ delta_gi)
{
  const int wv = threadIdx.x >> 6;
  const int e = blockIdx.x * 4 + wv;
  const int h = threadIdx.x & 63;
  const int u = edges[e * 2 + 0];
  const int v = edges[e * 2 + 1];
  __shared__ __align__(16) float xuv[4][64], ein[4][64], eout[4][64], dm[4][64];
  const float xuvh = x[((int64_t)u * 512 + v) * 64 + h];
  const float xvuh = x[((int64_t)v * 512 + u) * 64 + h];
  xuv[wv][h] = xuvh;
  const int nz_vu = __popcll(__ballot(xvuh != 0.f));
  const int nz_uv = __popcll(__ballot(xuvh != 0.f));
  float n_in = (float)(col_nz[u] - nz_vu) / 64.f;
  if (n_in == 0.f) n_in = 1.f;
  float n_out = (float)(col_nz[v] - nz_uv) / 64.f;
  if (n_out == 0.f) n_out = 1.f;
  ein[wv][h] = (col_sum[u * 64 + h] - xvuh) / n_in;
  eout[wv][h] = (col_sum[v * 64 + h] - xuvh) / n_out;
  __syncthreads();
  const float4* w1r = (const float4*)(w1 + h * 64);
  const float4* w2r = (const float4*)(w2 + h * 64);
  const float4* w3r = (const float4*)(w3 + h * 64);
  const float4* xuv4 = (const float4*)&xuv[wv][0];
  const float4* ein4 = (const float4*)&ein[wv][0];
  const float4* eout4 = (const float4*)&eout[wv][0];
  float acc = 0.f;
#pragma unroll
  for (int kk = 0; kk < 16; ++kk) {
    float4 a = xuv4[kk], b = w1r[kk];
    acc += a.x * b.x + a.y * b.y + a.z * b.z + a.w * b.w;
    a = ein4[kk]; b = w2r[kk];
    acc += a.x * b.x + a.y * b.y + a.z * b.z + a.w * b.w;
    a = eout4[kk]; b = w3r[kk];
    acc += a.x * b.x + a.y * b.y + a.z * b.z + a.w * b.w;
  }
  const float m = fmaxf(acc, 0.f);
  dm[wv][h] = m - xuvh;
  __syncthreads();
  const float4* dm4 = (const float4*)&dm[wv][0];
#pragma unroll
  for (int r = 0; r < 3; ++r) {
    const int gg = h + r * 64;
    const float4* wr = (const float4*)(w_ih + gg * 128);
    float d = 0.f;
#pragma unroll
    for (int kk = 0; kk < 16; ++kk) {
      float4 a = dm4[kk], b = wr[kk];
      d += a.x * b.x + a.y * b.y + a.z * b.z + a.w * b.w;
    }
    delta_gi[e * 192 + gg] = d;
  }
}

// ---- GRU scan (r8's v4 — measured best, 503 us/layer). ----
// 256 thr = 4 waves, one row per block. Waves 0-2 (producers): gate g = tid,
// wsum in 16 float4; x[t+1] prefetched in named regs via use-then-reload.
// Wave 3 (consumer): whh rows j/j+64/j+128 (48 float4); r,z,n computed
// locally; ONE lgkm-only barrier per step. The compiler remats weight loads
// from L2 per step (unavoidable in HIP source — r8-r15 ablations); this
// structure overlaps them best.
#define DECL_W(i)                                                              \
  float4 W##i; {                                                               \
    float4 t0 = LD4(wg + 4 * (i));                                             \
    float4 t1 = LD4(wg + 64 + 4 * (i));                                        \
    W##i.x = t0.x + t1.x; W##i.y = t0.y + t1.y;                                \
    W##i.z = t0.z + t1.z; W##i.w = t0.w + t1.w;                                \
  }                                                                            \
  PIN4(W##i);
#define DECL_X(i) float4 X##i = LD4(xrow + 4 * (i));
#define PQ(i, q) { DOT4(ac##q, X##i, W##i); X##i = LD4(xnext + 4 * (i)); }
#define DECL_WR(i) float4 WR##i = LD4(wr_ + 4 * (i)); PIN4(WR##i);
#define DECL_WZ(i) float4 WZ##i = LD4(wz_ + 4 * (i)); PIN4(WZ##i);
#define DECL_WN(i) float4 WN##i = LD4(wn_ + 4 * (i)); PIN4(WN##i);
#define CCHUNK(i)                                                              \
  { float4 hc = hs4[(i)];                                                      \
    DOT4(racc, hc, WR##i); DOT4(zacc, hc, WZ##i); DOT4(nacc, hc, WN##i); }

__global__ __launch_bounds__(256, 2) void scan_kernel(
    float* __restrict__ x, const float* __restrict__ delta_gi,
    const int* __restrict__ idxmap,
    const float* __restrict__ w_ih, const float* __restrict__ w_hh,
    const float* __restrict__ b_ih, const float* __restrict__ b_hh)
{
  const int b = blockIdx.x;
  const int tid = threadIdx.x;
  __shared__ __align__(16) float hs[64];
  __shared__ float gib[2][192];
  __shared__ int idxl[512];
  float* xrow = x + (int64_t)b * 32768;

  for (int i = tid; i < 512; i += 256) idxl[i] = idxmap[b * 512 + i];

  if (tid < 192) {
    // ---------------- producer ----------------
    const int g = tid;
    const float* wg = w_ih + g * 128;
    ALL16(DECL_W)
    const float bi = b_ih[g];
    ALL16(DECL_X)          // X = x[0]
    __syncthreads();       // idxl staged, hs inited
    {                      // prologue: gib[0] (and reload X <- x[1])
      float ac0 = bi, ac1 = 0.f, ac2 = 0.f, ac3 = 0.f;
      const float* xnext = xrow + 64;
      ALLQ(PQ)
      float acc = (ac0 + ac1) + (ac2 + ac3);
      const int i0 = idxl[0];
      if (i0 >= 0) acc += delta_gi[(int64_t)i0 * 192 + g];
      gib[0][g] = acc;
    }
    const int idx1 = idxl[1];
    float dgn = 0.f;
    if (idx1 >= 0) dgn = delta_gi[(int64_t)idx1 * 192 + g];
    barrier_lgkm();        // gib[0] published
    for (int t = 0; t < 512; ++t) {
      if (t < 511) {
        const int tn2 = (t + 2 < 512) ? (t + 2) : 511;
        const float* xnext = xrow + tn2 * 64;
        float ac0 = bi + dgn, ac1 = 0.f, ac2 = 0.f, ac3 = 0.f;
        ALLQ(PQ)           // consumes X = x[t+1], reloads X <- x[tn2]
        gib[(t + 1) & 1][g] = (ac0 + ac1) + (ac2 + ac3);
        const int idxn = idxl[tn2];
        dgn = 0.f;
        if (idxn >= 0) dgn = delta_gi[(int64_t)idxn * 192 + g];
      }
      barrier_lgkm();      // gib[t+1] published / h(t) published
    }
  } else {
    // ---------------- consumer ----------------
    const int j = tid - 192;
    const float* wr_ = w_hh + j * 64;
    const float* wz_ = w_hh + (j + 64) * 64;
    const float* wn_ = w_hh + (j + 128) * 64;
    ALL16(DECL_WR)
    ALL16(DECL_WZ)
    ALL16(DECL_WN)
    const float bhr = b_hh[j], bhz = b_hh[j + 64], bhn = b_hh[j + 128];
    float hj = 0.f;
    hs[j] = 0.f;
    __syncthreads();
    __builtin_amdgcn_s_setprio(1);  // consumer wave is the critical path
    barrier_lgkm();
    const float4* hs4 = (const float4*)hs;
    for (int t = 0; t < 512; ++t) {
      const float gr = gib[t & 1][j];
      const float gz = gib[t & 1][64 + j];
      const float gn = gib[t & 1][128 + j];
      float racc = bhr, zacc = bhz, nacc = bhn;
      ALL16(CCHUNK)
      const float r = fsig_(gr + racc);
      const float z = fsig_(gz + zacc);
      const float n = ftanh_(gn + r * nacc);
      hj = (1.f - z) * n + z * hj;
      hs[j] = hj;
      xrow[t * 64 + j] = hj;
      barrier_lgkm();      // h(t) published / next gib published
    }
  }
}

// One block per (path, direction). 7-step GRU, D=68, gates 204.
// graph_emb computed inline from col_sum (graphemb_kernel fused away).
__global__ __launch_bounds__(256) void path_kernel(
    const float* __restrict__ x, const int* __restrict__ paths,
    const float* __restrict__ demands, const float* __restrict__ wd,
    const float* __restrict__ col_sum,
    const float* __restrict__ wih_f, const float* __restrict__ whh_f,
    const float* __restrict__ bih_f, const float* __restrict__ bhh_f,
    const float* __restrict__ wih_b, const float* __restrict__ whh_b,
    const float* __restrict__ bih_b, const float* __restrict__ bhh_b,
    float* __restrict__ h_out)
{
  const int p = blockIdx.x & 63;
  const int dir = blockIdx.x >> 6;
  const int g = threadIdx.x;
  const float* w_ih = dir ? wih_b : wih_f;
  const float* w_hh = dir ? whh_b : whh_f;
  const float* bih = dir ? bih_b : bih_f;
  const float* bhh = dir ? bhh_b : bhh_f;
  __shared__ float feat[7][68], hs[68], rbuf[68], zbuf[68];
  if (g < 64) {  // graph_emb inline: mean over (i,j) = col_sum sum / 512^2
    float s = 0.f;
#pragma unroll 8
    for (int jj = 0; jj < 512; ++jj) s += col_sum[jj * 64 + g];
    hs[g] = s * (1.f / 262144.f);
  } else if (g < 68) {
    hs[g] = 0.f;
  }
  if (g < 68) {
#pragma unroll
    for (int t = 0; t < 7; ++t) {
      const int src = paths[p * 8 + t];
      const int dst = paths[p * 8 + t + 1];
      feat[t][g] = (g < 64) ? x[((int64_t)src * 512 + dst) * 64 + g]
                            : fmaxf(demands[p] * wd[g - 64], 0.f);
    }
  }
  __syncthreads();
  for (int s = 0; s < 7; ++s) {
    const int t = dir ? (6 - s) : s;
    float acc = 0.f, hacc = 0.f;
    if (g < 204) {
      acc = bih[g];
      hacc = bhh[g];
      for (int k = 0; k < 68; ++k) {
        acc += feat[t][k] * w_ih[g * 68 + k];
        hacc += hs[k] * w_hh[g * 68 + k];
      }
    }
    if (g < 68) rbuf[g] = sig_(acc + hacc);
    else if (g < 136) zbuf[g - 68] = sig_(acc + hacc);
    __syncthreads();
    if (g >= 136 && g < 204) {
      const int j = g - 136;
      const float n = tanhf(acc + rbuf[j] * hacc);
      const float z = zbuf[j];
      const float hn = (1.f - z) * n + z * hs[j];
      hs[j] = hn;
    }
    __syncthreads();
  }
  if (g < 68) h_out[(dir * 64 + p) * 68 + g] = hs[g];
}

__global__ __launch_bounds__(64) void combine_kernel(
    const float* __restrict__ h_out, const float* __restrict__ wq,
    const float* __restrict__ bq, float* __restrict__ out)
{
  const int p = threadIdx.x;
  float l = bq[0];
#pragma unroll
  for (int d = 0; d < 68; ++d)
    l += 0.5f * (h_out[p * 68 + d] + h_out[(64 + p) * 68 + d]) * wq[d];
  float mx = l;
#pragma unroll
  for (int off = 32; off > 0; off >>= 1) mx = fmaxf(mx, __shfl_xor(mx, off, 64));
  const float e = expf(l - mx);
  float s = e;
#pragma unroll
  for (int off = 32; off > 0; off >>= 1) s += __shfl_xor(s, off, 64);
  out[p] = e / s;
}

extern "C" void kernel_launch(void* const* d_in, const int* in_sizes, int n_in,
                              void* d_out, int out_size, void* d_ws, size_t ws_size,
                              hipStream_t stream)
{
  const float* adj = (const float*)d_in[0];
  const int* edges = (const int*)d_in[1];
  const int* paths = (const int*)d_in[2];
  const float* demands = (const float*)d_in[3];
  const float* emb_w = (const float*)d_in[4];
  const float* w1s = (const float*)d_in[5];
  const float* w2s = (const float*)d_in[6];
  const float* w3s = (const float*)d_in[7];
  const float* gru_w_ih = (const float*)d_in[8];
  const float* gru_w_hh = (const float*)d_in[9];
  const float* gru_b_ih = (const float*)d_in[10];
  const float* gru_b_hh = (const float*)d_in[11];
  const float* pf_w_ih = (const float*)d_in[12];
  const float* pf_w_hh = (const float*)d_in[13];
  const float* pf_b_ih = (const float*)d_in[14];
  const float* pf_b_hh = (const float*)d_in[15];
  const float* pb_w_ih = (const float*)d_in[16];
  const float* pb_w_hh = (const float*)d_in[17];
  const float* pb_b_ih = (const float*)d_in[18];
  const float* pb_b_hh = (const float*)d_in[19];
  const float* wq = (const float*)d_in[20];
  const float* bq = (const float*)d_in[21];
  const float* wd = (const float*)d_in[22];
  float* out = (float*)d_out;

  // Workspace layout (floats): ~74.6 MB total (known-safe size)
  float* xA = (float*)d_ws;                    // 512*512*64 = 16777216
  float* col_sum = xA + 16777216;              // 32768
  int* col_nz = (int*)(col_sum + 32768);       // 512
  int* idxmap = col_nz + 512;                  // 262144
  float* delta_gi = (float*)(idxmap + 262144); // 8192*192 = 1572864
  float* h_out = delta_gi + 1572864;           // 2*64*68 = 8704

  hipMemsetAsync(idxmap, 0xFF, 262144 * sizeof(int), stream);
  scatter_idx_kernel<<<32, 256, 0, stream>>>(edges, idxmap);
  embed_kernel<<<65536, 256, 0, stream>>>(adj, emb_w, xA);

  for (int t = 0; t < 3; ++t) {
    colsum_kernel<<<512, 256, 0, stream>>>(xA, col_sum, col_nz);
    edge_kernel<<<2048, 256, 0, stream>>>(xA, edges, col_sum, col_nz,
        w1s + t * 4096, w2s + t * 4096, w3s + t * 4096, gru_w_ih, delta_gi);
    scan_kernel<<<512, 256, 0, stream>>>(xA, delta_gi, idxmap,
        gru_w_ih, gru_w_hh, gru_b_ih, gru_b_hh);
  }

  colsum_kernel<<<512, 256, 0, stream>>>(xA, col_sum, col_nz);
  path_kernel<<<128, 256, 0, stream>>>(xA, paths, demands, wd, col_sum,
      pf_w_ih, pf_w_hh, pf_b_ih, pf_b_hh,
      pb_w_ih, pb_w_hh, pb_b_ih, pb_b_hh, h_out);
  combine_kernel<<<1, 64, 0, stream>>>(h_out, wq, bq, out);
}